// Round 5
// baseline (11011.887 us; speedup 1.0000x reference)
//
#include <hip/hip_runtime.h>
#include <math.h>

#define TT 19
#define TPREV 10

typedef __attribute__((ext_vector_type(8))) short bf8v;
typedef __attribute__((ext_vector_type(4))) float f4v;
typedef __attribute__((ext_vector_type(16))) float f16v;

__device__ __forceinline__ float sigmoidf_(float x){ return 1.f/(1.f+expf(-x)); }
__device__ __forceinline__ unsigned short f2bf(float x){
    unsigned int u = __float_as_uint(x);
    u += 0x7FFFu + ((u>>16)&1u);
    return (unsigned short)(u>>16);
}
__device__ __forceinline__ float bf2f(unsigned short b){ return __uint_as_float(((unsigned int)b)<<16); }

// RULE (R4, keep forever): NEVER use the offset-immediate arg of
// global_load_lds — it corrupts the LDS destination address. offset=0 +
// explicit pointer arithmetic only.
#define GLDS(g, l) __builtin_amdgcn_global_load_lds( \
    (const __attribute__((address_space(1))) void*)(g),   \
    (__attribute__((address_space(3))) void*)(l), 16, 0, 0)

struct HSeg {
    const unsigned short* in;
    int cl;        // log2(Cin) of the input buffer layout (5,7,8)
    int c0;        // absolute ci base
    int nch;       // number of 32-ci chunks
    int tap0, ntaps, five;
};
struct HJob {
    const unsigned short* wt;   // tile stream
    float* out;
    int cout_stride, pad;
    HSeg s;
};
struct HJobs14 { HJob j[14]; };
struct HJobs9  { HJob j[9]; };

// sH PLANE LAYOUT (kept from R4; verified 8.7M -> 1.3M conflicts):
// 4 ci-octet planes x [cell][8 shorts]; B-read = 16B/lane stride ->
// any 8 consecutive lanes cover all 32 banks once.
__device__ __forceinline__ void stage_halo(
    unsigned short* sH, const unsigned short* inb, int cl, int c0,
    int y0, int tid)
{
#pragma unroll
    for (int k = 0; k < 8; ++k) {
        const int s = tid + k * 256;
        if (s < 1920) {
            const int r = s / 160;
            const int rem = s - r * 160;
            const int cc = rem >> 2, G = rem & 3;
            const int y = y0 + r - 2, x = cc - 4;
            const bool okv = ((unsigned)y < 32u) & ((unsigned)x < 32u);
            const int yc = okv ? y : 0, xc = okv ? x : 0;
            bf8v v = *(const bf8v*)(inb + ((((yc << 5) + xc)) << cl) + c0 + G * 8);
            if (!okv) v = (bf8v)(short)0;
            *(bf8v*)&sH[(G * 480 + r * 40 + cc) * 8] = v;
        }
    }
}

// ------------------------------------------------------------------
// hconvA (R5): 2-taps-per-barrier group pipeline.
//   R4 post-mortem: per-tap barrier forced read-phase/MFMA-phase
//   lockstep across all waves -> LDS (1152 cyc/tap/CU) and MFMA
//   (1024 cyc/tap/CU) pipes SERIALIZED (2592 cyc/tap measured).
//   Fix: one barrier per 2 taps; issue all 24 ds_reads (both taps,
//   statically-named regs) before the 32-MFMA cluster. Waves drift
//   within the group window -> one wave's reads overlap another's
//   MFMA stalls; compiler's counted lgkmcnt lets early MFMAs start
//   while later reads are in flight.
//   ONLY FOR ntaps==25, five==1 jobs (all phase-A jobs). Per chunk:
//   12 pair-groups + 1 single-group.
//   Slot ledger (4 x 8KB slots in sA, group parity p=gg&1):
//   - group gg consumes slots {2p, 2p+1} (single group: slot 2p).
//   - [I] at group gg targets slots {2(p^1),...} = last read at group
//     gg-1; every wave passed barrier(gg) after finishing gg-1 -> no
//     overwrite race.
//   - tiles of group gg resident at barrier(gg): each wave's
//     vmcnt(0) (own GLDS complete) precedes its barrier arrival.
//   - vmcnt(0) is cheap: issue->wait lead = 1 full group (~2500 cyc)
//     >> 900-cyc HBM latency. Chunk restage __syncthreads over-drains
//     once per chunk (acceptable).
//   - barrier counts are block-uniform (nch, 13 groups) -> no deadlock.
// ------------------------------------------------------------------
template<typename JOBS>
__global__ __launch_bounds__(256, 2) void hconvA_kernel(JOBS jobs)
{
    __shared__ unsigned short sA[16384];   // 4 tile slots x 8KB
    __shared__ unsigned short sH[15360];   // 4 planes x 480 cells x 8 shorts
    const int tid = threadIdx.x;

    // XCD-clustered job mapping (requires nb%8==0, gridDim.x==32)
    const int nb   = gridDim.x * gridDim.y;
    const int per8 = nb >> 3;
    const int bidl = blockIdx.x + gridDim.x * blockIdx.y;
    const int g    = (bidl & 7) * per8 + (bidl >> 3);
    const int jy   = g >> 5;
    const int xt   = g & 31;
    const HJob jb = jobs.j[jy];

    const int ng0 = xt << 8;
    const int bb = ng0 >> 10, p0 = ng0 & 1023;
    const int y0 = p0 >> 5;          // {0,8,16,24}

    const int lane = tid & 63, wv = tid >> 6;
    const int wm = (wv & 1) << 6;    // M base 0/64
    const int wn = (wv >> 1) << 7;   // N base 0/128
    const int col = lane & 31, ll5 = lane >> 5;

    int bofs0[4];
#pragma unroll
    for (int ni = 0; ni < 4; ++ni) {
        const int ln = wn + ni * 32 + col;
        const int cell = ((ln >> 5) + 2) * 40 + (ln & 31) + 4;
        bofs0[ni] = cell * 8 + ll5 * 3840;
    }
    const int rowA0 = (wm + col) * 8;
    const int oA = ll5 * 1024;

    f16v acc[2][4];
#pragma unroll
    for (int i = 0; i < 2; ++i)
#pragma unroll
        for (int j = 0; j < 4; ++j) acc[i][j] = (f16v)0.f;

    const HSeg sg = jb.s;
    const unsigned short* inb = sg.in + ((size_t)bb << (10 + sg.cl));
    const unsigned short* wissue = jb.wt;
    const int nch = sg.nch;

    stage_halo(sH, inb, sg.cl, sg.c0, y0, tid);
    // prologue: group 0 (tiles 0,1) -> slots 0,1
    GLDS(wissue + tid * 8,                &sA[tid * 8]);
    GLDS(wissue + (tid + 256) * 8,        &sA[(tid + 256) * 8]);
    GLDS(wissue + 4096 + tid * 8,         &sA[4096 + tid * 8]);
    GLDS(wissue + 4096 + (tid + 256) * 8, &sA[4096 + (tid + 256) * 8]);
    wissue += 8192;

    int gg = 0;
    for (int c = 0; c < nch; ++c) {
        if (c > 0) {
            __syncthreads();   // all waves done reading sH; drains queues
            stage_halo(sH, inb, sg.cl, sg.c0 + c * 32, y0, tid);
        }
        const bool last = (c == nch - 1);
        for (int j = 0; j < 13; ++j, ++gg) {
            // [W]+[B]: own GLDS (group gg) + own ds_writes complete, then
            // all-waves sync -> tiles resident, prior readers done.
            asm volatile("s_waitcnt vmcnt(0) lgkmcnt(0)" ::: "memory");
            __builtin_amdgcn_s_barrier();
            __builtin_amdgcn_sched_barrier(0);
            // [I]: issue next group's tiles into opposite slot pair
            const int nIss = (j == 11) ? 1 : ((j == 12) ? (last ? 0 : 2) : 2);
            const int sb1 = ((gg + 1) & 1) << 1;
            for (int q = 0; q < nIss; ++q) {
                GLDS(wissue + tid * 8,         &sA[(sb1 + q) * 4096 + tid * 8]);
                GLDS(wissue + (tid + 256) * 8, &sA[(sb1 + q) * 4096 + (tid + 256) * 8]);
                wissue += 4096;
            }
            // [R]: all reads for both taps (statically-named regs)
            const int sb0 = (gg & 1) << 1;
            const int k0 = j << 1;           // tap-in-chunk (j=12 -> 24)
            const bool pair = (j < 12);
            int t5 = (k0 * 52) >> 8;
            const int tOa = ((t5 - 2) * 40 + (k0 - t5 * 5 - 2)) * 8;
            const unsigned short* sA0 = &sA[sb0 * 4096];
            bf8v av0[2][2], bv0[2][4], av1[2][2], bv1[2][4];
#pragma unroll
            for (int s = 0; s < 2; ++s) {
#pragma unroll
                for (int mi = 0; mi < 2; ++mi)
                    av0[s][mi] = *(const bf8v*)&sA0[s * 2048 + oA + rowA0 + mi * 256];
#pragma unroll
                for (int ni = 0; ni < 4; ++ni)
                    bv0[s][ni] = *(const bf8v*)&sH[bofs0[ni] + tOa + s * 7680];
            }
            if (pair) {
                const int k1 = k0 + 1;
                t5 = (k1 * 52) >> 8;
                const int tOb = ((t5 - 2) * 40 + (k1 - t5 * 5 - 2)) * 8;
                const unsigned short* sA1 = &sA[(sb0 + 1) * 4096];
#pragma unroll
                for (int s = 0; s < 2; ++s) {
#pragma unroll
                    for (int mi = 0; mi < 2; ++mi)
                        av1[s][mi] = *(const bf8v*)&sA1[s * 2048 + oA + rowA0 + mi * 256];
#pragma unroll
                    for (int ni = 0; ni < 4; ++ni)
                        bv1[s][ni] = *(const bf8v*)&sH[bofs0[ni] + tOb + s * 7680];
                }
            }
            // [M]: MFMA cluster (compiler inserts counted lgkm waits)
            __builtin_amdgcn_s_setprio(1);
#pragma unroll
            for (int s = 0; s < 2; ++s)
#pragma unroll
                for (int mi = 0; mi < 2; ++mi)
#pragma unroll
                    for (int ni = 0; ni < 4; ++ni)
                        acc[mi][ni] = __builtin_amdgcn_mfma_f32_32x32x16_bf16(
                            av0[s][mi], bv0[s][ni], acc[mi][ni], 0, 0, 0);
            if (pair) {
#pragma unroll
                for (int s = 0; s < 2; ++s)
#pragma unroll
                    for (int mi = 0; mi < 2; ++mi)
#pragma unroll
                        for (int ni = 0; ni < 4; ++ni)
                            acc[mi][ni] = __builtin_amdgcn_mfma_f32_32x32x16_bf16(
                                av1[s][mi], bv1[s][ni], acc[mi][ni], 0, 0, 0);
            }
            __builtin_amdgcn_s_setprio(0);
        }
    }

    // epilogue (32x32 C/D): col=lane&31, row=(reg&3)+8*(reg>>2)+4*ll5
    const int nfix = ng0 + wn + col;
#pragma unroll
    for (int ni = 0; ni < 4; ++ni) {
        const int n = nfix + ni * 32;
        float* ob = jb.out + (size_t)n * jb.cout_stride;
#pragma unroll
        for (int mi = 0; mi < 2; ++mi) {
            const int mb = wm + mi * 32 + 4 * ll5;
            const f16v a = acc[mi][ni];
#pragma unroll
            for (int qd = 0; qd < 4; ++qd) {
                f4v v;
                v[0] = a[qd * 4 + 0]; v[1] = a[qd * 4 + 1];
                v[2] = a[qd * 4 + 2]; v[3] = a[qd * 4 + 3];
                *(f4v*)(ob + mb + qd * 8) = v;
            }
        }
    }
}

// ------------------------------------------------------------------
// hconv: classic 2-phase stream conv (phase B: many short jobs, 576
// blocks). sH plane layout (4 planes x 320 cells x 8 shorts).
// ------------------------------------------------------------------
template<typename JOBS>
__global__ __launch_bounds__(256) void hconv_kernel(JOBS jobs)
{
    __shared__ unsigned short sA[8192];    // 2 x 8KB tile buffers
    __shared__ unsigned short sH[10240];   // 4 planes x 320 cells x 8 shorts
    const HJob jb = jobs.j[blockIdx.y];
    const int tid = threadIdx.x;

    const int ng0 = blockIdx.x * 128;
    const int bb = ng0 >> 10, p0 = ng0 & 1023;
    const int y0 = p0 >> 5;

    const int lane = tid & 63, wv = tid >> 6;
    const int wm = (wv & 1) << 6;
    const int wn = (wv >> 1) << 6;
    const int col = lane & 31, ll5 = lane >> 5;

    int bofs0[2];
#pragma unroll
    for (int ni = 0; ni < 2; ++ni) {
        const int ln = wn + ni * 32 + col;
        const int cell = ((ln >> 5) + 2) * 40 + (ln & 31) + 4;
        bofs0[ni] = cell * 8 + ll5 * 2560;
    }

    f16v acc[2][2];
#pragma unroll
    for (int i = 0; i < 2; ++i)
#pragma unroll
        for (int j = 0; j < 2; ++j) acc[i][j] = (f16v)0.f;

    const HSeg sg = jb.s;
    const unsigned short* inb = sg.in + ((size_t)bb << (10 + sg.cl));
    const unsigned short* wptr = jb.wt;
    int buf = 0;
    bool first = true;
    for (int ch = 0; ch < sg.nch; ++ch) {
        const int c0 = sg.c0 + ch * 32;
#pragma unroll
        for (int k = 0; k < 5; ++k) {
            const int s = tid + k * 256;
            const int r = s / 160;
            const int rem = s - r * 160;
            const int cc = rem >> 2, G = rem & 3;
            const int y = y0 + r - 2, x = cc - 4;
            const bool okv = ((unsigned)y < 32u) & ((unsigned)x < 32u);
            const int yc = okv ? y : 0, xc = okv ? x : 0;
            bf8v v = *(const bf8v*)(inb + ((((yc << 5) + xc)) << sg.cl) + c0 + G * 8);
            if (!okv) v = (bf8v)(short)0;
            *(bf8v*)&sH[(G * 320 + r * 40 + cc) * 8] = v;
        }
        if (first) {
            GLDS(wptr + tid * 8,         &sA[tid * 8]);
            GLDS(wptr + (tid + 256) * 8, &sA[(tid + 256) * 8]);
            wptr += 4096;
            first = false;
        }
        __syncthreads();
        for (int t = 0; t < sg.ntaps; ++t) {
            GLDS(wptr + tid * 8,         &sA[(buf ^ 1) * 4096 + tid * 8]);
            GLDS(wptr + (tid + 256) * 8, &sA[(buf ^ 1) * 4096 + (tid + 256) * 8]);
            wptr += 4096;
            int tO = 0;
            if (sg.five) {
                const int tap = sg.tap0 + t;
                const int t5 = (tap * 52) >> 8;
                tO = ((t5 - 2) * 40 + (tap - t5 * 5 - 2)) * 8;
            }
            const unsigned short* sAb = &sA[buf * 4096];
#pragma unroll
            for (int s = 0; s < 2; ++s) {
                const int o = s * 2 + ll5;
                bf8v av[2], bv[2];
#pragma unroll
                for (int mi = 0; mi < 2; ++mi)
                    av[mi] = *(const bf8v*)&sAb[(o * 128 + wm + mi * 32 + col) * 8];
#pragma unroll
                for (int ni = 0; ni < 2; ++ni)
                    bv[ni] = *(const bf8v*)&sH[bofs0[ni] + tO + s * 5120];
#pragma unroll
                for (int mi = 0; mi < 2; ++mi)
#pragma unroll
                    for (int ni = 0; ni < 2; ++ni)
                        acc[mi][ni] = __builtin_amdgcn_mfma_f32_32x32x16_bf16(
                            av[mi], bv[ni], acc[mi][ni], 0, 0, 0);
            }
            __syncthreads();
            buf ^= 1;
        }
    }

    const int nfix = ng0 + wn + col;
#pragma unroll
    for (int ni = 0; ni < 2; ++ni) {
        const int n = nfix + ni * 32;
        float* ob = jb.out + (size_t)n * jb.cout_stride;
#pragma unroll
        for (int mi = 0; mi < 2; ++mi) {
            const int mb = wm + mi * 32 + 4 * ll5;
            const f16v a = acc[mi][ni];
#pragma unroll
            for (int qd = 0; qd < 4; ++qd) {
                f4v v;
                v[0] = a[qd * 4 + 0]; v[1] = a[qd * 4 + 1];
                v[2] = a[qd * 4 + 2]; v[3] = a[qd * 4 + 3];
                *(f4v*)(ob + mb + qd * 8) = v;
            }
        }
    }
}

// ------------------------------------------------------------------
// packT: OIHW f32 -> linear tile stream [at][oct][row][8] bf16.
// ------------------------------------------------------------------
__global__ __launch_bounds__(256) void packT_kernel(
    const float* __restrict__ src, unsigned short* __restrict__ dst,
    int Cin, int srcTaps, int rowOff, int ci0, int ntaps, int tap0,
    int ciMax, int total)
{
    const int idx = blockIdx.x * 256 + threadIdx.x;
    if (idx >= total) return;
    const int j = idx & 7;
    const int row = (idx >> 3) & 127;
    const int q = (idx >> 10) & 3;
    const int at = idx >> 12;
    const int ch = at / ntaps;
    const int tap = tap0 + (at - ch * ntaps);
    const int ci = ci0 + ch * 32 + q * 8 + j;
    float v = 0.f;
    if (ci < ciMax)
        v = src[((size_t)(rowOff + row) * Cin + ci) * srcTaps + tap];
    dst[idx] = f2bf(v);
}

__global__ __launch_bounds__(256) void net_kernel(
    const float* __restrict__ frames, const float* __restrict__ mask,
    const float* __restrict__ xgen, unsigned short* __restrict__ net, int t)
{
    const int idx = blockIdx.x * 256 + threadIdx.x;  // 8192*32
    const int n = idx >> 5, ch = idx & 31;
    float v = 0.f;
    if (ch < 16) {
        const int b = n >> 10, p = n & 1023;
        const float fr = frames[((((size_t)b * 20 + t) << 10) + p) * 16 + ch];
        if (t < TPREV) v = fr;
        else {
            const float mk = mask[((((size_t)b * 9 + (t - TPREV)) << 10) + p) * 16 + ch];
            v = mk * fr + (1.f - mk) * xgen[(size_t)n * 16 + ch];
        }
    }
    net[idx] = f2bf(v);
}

__global__ __launch_bounds__(256) void gates_kernel(
    const float* __restrict__ preA, const float* __restrict__ preB,
    float* __restrict__ c, float* __restrict__ m,
    unsigned short* __restrict__ m_bf, unsigned short* __restrict__ mem)
{
    const int idx = blockIdx.x * 256 + threadIdx.x;  // 8192*128
    const int n = idx >> 7, ch = idx & 127;
    const float* pa = preA + (size_t)n * 896 + ch;
    const float* pb = preB + (size_t)n * 896 + ch;
    const float i_ = pa[0]   + pb[0];
    const float f_ = pa[128] + pb[128];
    const float g_ = pa[256] + pb[256];
    const float ip = pa[384] + pb[384];
    const float fp = pa[512] + pb[512];
    const float gp = pa[640] + pb[640];
    const float cn = sigmoidf_(f_ + 1.f) * c[idx] + sigmoidf_(i_) * tanhf(g_);
    const float mn = sigmoidf_(fp + 1.f) * m[idx] + sigmoidf_(ip) * tanhf(gp);
    c[idx] = cn;
    m[idx] = mn;
    m_bf[idx] = f2bf(mn);
    mem[(size_t)n * 256 + ch] = f2bf(cn);
    mem[(size_t)n * 256 + 128 + ch] = f2bf(mn);
}

__global__ __launch_bounds__(256) void hout_kernel(
    const float* __restrict__ preA, const float* __restrict__ preB,
    const float* __restrict__ opart, const float* __restrict__ lconv,
    unsigned short* __restrict__ h)
{
    const int idx = blockIdx.x * 256 + threadIdx.x;  // 8192*128
    const int n = idx >> 7, ch = idx & 127;
    float oc = preA[(size_t)n * 896 + 768 + ch] + preB[(size_t)n * 896 + 768 + ch];
#pragma unroll
    for (int j = 0; j < 8; ++j) oc += opart[idx + (size_t)j * 1048576];
    h[idx] = f2bf(sigmoidf_(oc) * tanhf(lconv[idx]));
}

__global__ __launch_bounds__(256) void wout_kernel(
    const unsigned short* __restrict__ h3, const float* __restrict__ wo,
    float* __restrict__ xgen, float* __restrict__ out, int t)
{
    const int idx = blockIdx.x * 256 + threadIdx.x;  // 8192*16
    const int n = idx >> 4, ch = idx & 15;
    const int b = n >> 10, p = n & 1023;
    const unsigned short* hr = h3 + (size_t)n * 128;
    const float* wr = wo + ch * 128;
    float acc = 0.f;
#pragma unroll 8
    for (int ci = 0; ci < 128; ++ci)
        acc = fmaf(bf2f(hr[ci]), wr[ci], acc);
    xgen[idx] = acc;
    out[((((size_t)b * TT + t) << 10) + p) * 16 + ch] = acc;
}

extern "C" void kernel_launch(void* const* d_in, const int* in_sizes, int n_in,
                              void* d_out, int out_size, void* d_ws, size_t ws_size,
                              hipStream_t stream)
{
    const float* frames = (const float*)d_in[0];
    const float* mask   = (const float*)d_in[1];
    const float* Wx0    = (const float*)d_in[2];
    const float* Wx     = (const float*)d_in[3];
    const float* Wh     = (const float*)d_in[4];
    const float* Wm     = (const float*)d_in[5];
    const float* Wo     = (const float*)d_in[6];
    const float* Wl     = (const float*)d_in[7];
    const float* Wout   = (const float*)d_in[8];
    float* out = (float*)d_out;

    char* base = (char*)d_ws;
    size_t off = 0;
    auto take = [&](size_t bytes) -> char* {
        char* p = base + off;
        off = (off + bytes + 255) & ~(size_t)255;
        return p;
    };
    // ---- zero-init region ----
    float* c0            = (float*)take(4ull * 1048576 * 4);
    float* m32           = (float*)take((size_t)1048576 * 4);
    unsigned short* hbf  = (unsigned short*)take(4ull * 1048576 * 2);
    unsigned short* mbf  = (unsigned short*)take((size_t)1048576 * 2);
    const size_t zbytes = off;
    // ---- working buffers ----
    float* xgen          = (float*)take((size_t)131072 * 4);
    float* preA          = (float*)take((size_t)8192 * 896 * 4);
    float* preB          = (float*)take((size_t)8192 * 896 * 4);
    float* lconv         = (float*)take((size_t)1048576 * 4);
    float* opart         = (float*)take(8ull * 1048576 * 4);
    unsigned short* net  = (unsigned short*)take((size_t)262144 * 2);   // [8192][32]
    unsigned short* mem  = (unsigned short*)take((size_t)2097152 * 2);
    // ---- packed weights (tile streams; +4096 el pad) ----
    unsigned short* pa0xT = (unsigned short*)take(((size_t)7 * 25 * 4096 + 4096) * 2);
    unsigned short* paT0 = (unsigned short*)take(((size_t)7 * 100 * 4096 + 4096) * 2);
    unsigned short* paT1 = (unsigned short*)take(((size_t)7 * 200 * 4096 + 4096) * 2);
    unsigned short* paT2 = (unsigned short*)take(((size_t)7 * 200 * 4096 + 4096) * 2);
    unsigned short* paT3 = (unsigned short*)take(((size_t)7 * 200 * 4096 + 4096) * 2);
    unsigned short* paT[4] = { paT0, paT1, paT2, paT3 };
    unsigned short* oT   = (unsigned short*)take((4ull * 200 * 4096 + 4096) * 2);
    unsigned short* lT   = (unsigned short*)take((4ull * 8 * 4096 + 4096) * 2);

    hipMemsetAsync(d_ws, 0, zbytes, stream);

    auto packT = [&](const float* s, unsigned short* d, int Cin, int srcTaps,
                     int rowOff, int ci0, int nch, int ntaps, int tap0, int ciMax) {
        const int total = nch * ntaps * 4096;
        packT_kernel<<<(total + 255) / 256, 256, 0, stream>>>(
            s, d, Cin, srcTaps, rowOff, ci0, ntaps, tap0, ciMax, total);
    };
    const int CIMAXBIG = 1 << 30;
    for (int g = 0; g < 7; ++g) {
        packT(Wx0, pa0xT + (size_t)g * 25 * 4096, 16, 25, g * 128, 0, 1, 25, 0, 16);
        const float* hm0 = (g < 3) ? (Wh + (size_t)g * 128 * 128 * 25)
                         : (g == 6) ? (Wh + (size_t)384 * 128 * 25)
                                    : (Wm + (size_t)(g - 3) * 128 * 128 * 25);
        packT(hm0, paT0 + (size_t)g * 100 * 4096, 128, 25, 0, 0, 4, 25, 0, CIMAXBIG);
        for (int l = 1; l < 4; ++l) {
            packT(Wx + (size_t)(l - 1) * 896 * 128 * 25,
                  paT[l] + (size_t)g * 200 * 4096, 128, 25, g * 128, 0, 4, 25, 0, CIMAXBIG);
            const float* hmsrc = (g < 3) ? (Wh + ((size_t)l * 512 + g * 128) * 128 * 25)
                               : (g == 6) ? (Wh + ((size_t)l * 512 + 384) * 128 * 25)
                                          : (Wm + ((size_t)l * 384 + (g - 3) * 128) * 128 * 25);
            packT(hmsrc, paT[l] + ((size_t)g * 200 + 100) * 4096, 128, 25, 0, 0, 4, 25, 0, CIMAXBIG);
        }
    }
    for (int l = 0; l < 4; ++l) {
        packT(Wo + (size_t)l * 128 * 256 * 25, oT + (size_t)l * 200 * 4096,
              256, 25, 0, 0, 8, 25, 0, CIMAXBIG);
        packT(Wl + (size_t)l * 128 * 256, lT + (size_t)l * 8 * 4096,
              256, 1, 0, 0, 8, 1, 0, CIMAXBIG);
    }

    for (int t = 0; t < TT; ++t) {
        net_kernel<<<1024, 256, 0, stream>>>(frames, mask, xgen, net, t);
        for (int l = 0; l < 4; ++l) {
            unsigned short* hl = hbf + (size_t)l * 1048576;
            // ---- phase A: one hconvA dispatch of 14 jobs ----
            HJobs14 JA{};
            if (l == 0) {
                for (int g = 0; g < 7; ++g) {
                    const unsigned short* hmsrc = (g < 3 || g == 6) ? hl : mbf;
                    JA.j[2 * g] = HJob{ pa0xT + (size_t)g * 25 * 4096, preA + g * 128,
                                        896, 0, HSeg{ net, 5, 0, 1, 0, 25, 1 } };
                    JA.j[2 * g + 1] = HJob{ paT0 + (size_t)g * 100 * 4096, preB + g * 128,
                                            896, 0, HSeg{ hmsrc, 7, 0, 4, 0, 25, 1 } };
                }
            } else {
                for (int g = 0; g < 7; ++g) {
                    const unsigned short* hmsrc = (g < 3 || g == 6) ? hl : mbf;
                    JA.j[g] = HJob{ paT[l] + (size_t)g * 200 * 4096, preA + g * 128,
                                    896, 0, HSeg{ hbf + (size_t)(l - 1) * 1048576, 7, 0, 4, 0, 25, 1 } };
                    JA.j[7 + g] = HJob{ paT[l] + ((size_t)g * 200 + 100) * 4096, preB + g * 128,
                                        896, 0, HSeg{ hmsrc, 7, 0, 4, 0, 25, 1 } };
                }
            }
            hconvA_kernel<HJobs14><<<dim3(32, 14), 256, 0, stream>>>(JA);

            gates_kernel<<<4096, 256, 0, stream>>>(preA, preB,
                c0 + (size_t)l * 1048576, m32, mbf, mem);

            // ---- phase B: o-conv split by ci-chunk x8 + lconv (classic kernel)
            HJobs9 JB{};
            for (int jj = 0; jj < 8; ++jj)
                JB.j[jj] = HJob{ oT + ((size_t)l * 200 + jj * 25) * 4096,
                                 opart + (size_t)jj * 1048576, 128, 0,
                                 HSeg{ mem, 8, jj * 32, 1, 0, 25, 1 } };
            JB.j[8] = HJob{ lT + (size_t)l * 8 * 4096, lconv, 128, 0,
                            HSeg{ mem, 8, 0, 8, 0, 1, 0 } };
            hconv_kernel<HJobs9><<<dim3(64, 9), 256, 0, stream>>>(JB);

            hout_kernel<<<4096, 256, 0, stream>>>(preA, preB, opart, lconv, hl);
        }
        wout_kernel<<<512, 256, 0, stream>>>(hbf + (size_t)3 * 1048576, Wout, xgen, out, t);
    }
}

// Round 6
// 10894.717 us; speedup vs baseline: 1.0108x; 1.0108x over previous
//
#include <hip/hip_runtime.h>
#include <math.h>

#define TT 19
#define TPREV 10

typedef __attribute__((ext_vector_type(8))) short bf8v;
typedef __attribute__((ext_vector_type(4))) float f4v;
typedef __attribute__((ext_vector_type(16))) float f16v;

__device__ __forceinline__ float sigmoidf_(float x){ return 1.f/(1.f+expf(-x)); }
__device__ __forceinline__ unsigned short f2bf(float x){
    unsigned int u = __float_as_uint(x);
    u += 0x7FFFu + ((u>>16)&1u);
    return (unsigned short)(u>>16);
}
__device__ __forceinline__ float bf2f(unsigned short b){ return __uint_as_float(((unsigned int)b)<<16); }

// RULE (R4, keep forever): NEVER use the offset-immediate arg of
// global_load_lds — it corrupts the LDS destination address. offset=0 +
// explicit pointer arithmetic only.
#define GLDS(g, l) __builtin_amdgcn_global_load_lds( \
    (const __attribute__((address_space(1))) void*)(g),   \
    (__attribute__((address_space(3))) void*)(l), 16, 0, 0)

struct HSeg {
    const unsigned short* in;
    int cl;        // log2(Cin) of the input buffer layout (5,7,8)
    int c0;        // absolute ci base
    int nch;       // number of 32-ci chunks
    int tap0, ntaps, five;
};
struct HJob {
    const unsigned short* wt;   // tile stream
    float* out;
    int cout_stride, pad;
    HSeg s;
};
struct HJobs14 { HJob j[14]; };
struct HJobs9  { HJob j[9]; };

// sH PLANE LAYOUT (kept from R4; verified 8.7M -> 1.3M conflicts):
// 4 ci-octet planes x [cell][8 shorts]; B-read = 16B/lane stride ->
// any 8 consecutive lanes cover all 32 banks once.
__device__ __forceinline__ void stage_halo(
    unsigned short* sH, const unsigned short* inb, int cl, int c0,
    int y0, int tid)
{
#pragma unroll
    for (int k = 0; k < 8; ++k) {
        const int s = tid + k * 256;
        if (s < 1920) {
            const int r = s / 160;
            const int rem = s - r * 160;
            const int cc = rem >> 2, G = rem & 3;
            const int y = y0 + r - 2, x = cc - 4;
            const bool okv = ((unsigned)y < 32u) & ((unsigned)x < 32u);
            const int yc = okv ? y : 0, xc = okv ? x : 0;
            bf8v v = *(const bf8v*)(inb + ((((yc << 5) + xc)) << cl) + c0 + G * 8);
            if (!okv) v = (bf8v)(short)0;
            *(bf8v*)&sH[(G * 480 + r * 40 + cc) * 8] = v;
        }
    }
}

// ------------------------------------------------------------------
// hconvA (R6): register software pipeline, B-prefetch.
//   R5 post-mortem: ANY schedule where reads for step t sit between
//   barrier(t) and MFMA(t) keeps all waves phase-locked: LDS pipe and
//   MFMA pipe alternate instead of overlapping (2592 cyc/tap = LDS
//   1152 + MFMA 1024 + sync, measured twice).
//   Fix (this version): per wave, prefetch the NEXT tap's B-fragments
//   (sH is CONSTANT within a chunk -> B-reads need no barrier!) before
//   the current MFMA cluster. The 16 MFMAs wait only on the 4 A-reads
//   (lgkmcnt(8) leaves the B-prefetch outstanding), so the 8 B-reads
//   execute on the LDS pipe UNDER the MFMA cluster.
//   Per tap t: [issue GLDS t+2][vmcnt(2)][barrier][rdA(t)][rdB(t+1)]
//              [MFMA(t) = A(t) x B-prefetched(t)].
//   Ledger (slots = tile&3, 4 x 8KB):
//   - before issue at tap t: outstanding = tile t+1 (2 loads);
//     after issue t+2: 4; vmcnt(2) retires tile t+1. Tile t was
//     retired at tap t-1 -> rdA(t) safe after barrier (covers other
//     waves' GLDS).
//   - slot (t+2)&3 overwrite: last read at tap t-2, >=2 barriers
//     before the issue -> no race.
//   - when issue clamped (stream end): vmcnt(0) instead (exact).
//   - chunk boundary: syncthreads (drain) + restage + syncthreads,
//     then rdB(tap0); ledger restarts clean (all issued resident).
//   - barrier counts block-uniform -> no deadlock.
//   - NO sched_barrier in the loop: MFMA operand ordering is pure C++
//     dataflow (compiler-tracked lgkmcnt); asm waits only order the
//     memory ops around them ("memory" clobber).
//   Specialized: ntaps==25 (all phase-A jobs). VGPR budget: bvA+bvB
//   64 + av 16 + addr ~= 110 VGPR + 128 acc AGPR -> fits 2 blocks/CU.
// ------------------------------------------------------------------
template<typename JOBS>
__global__ __launch_bounds__(256, 2) void hconvA_kernel(JOBS jobs)
{
    __shared__ unsigned short sA[16384];   // 4 tile slots x 8KB
    __shared__ unsigned short sH[15360];   // 4 planes x 480 cells x 8 shorts
    const int tid = threadIdx.x;

    // XCD-clustered job mapping (requires nb%8==0, gridDim.x==32)
    const int nb   = gridDim.x * gridDim.y;
    const int per8 = nb >> 3;
    const int bidl = blockIdx.x + gridDim.x * blockIdx.y;
    const int g    = (bidl & 7) * per8 + (bidl >> 3);
    const int jy   = g >> 5;
    const int xt   = g & 31;
    const HJob jb = jobs.j[jy];

    const int ng0 = xt << 8;
    const int bb = ng0 >> 10, p0 = ng0 & 1023;
    const int y0 = p0 >> 5;          // {0,8,16,24}

    const int lane = tid & 63, wv = tid >> 6;
    const int wm = (wv & 1) << 6;    // M base 0/64
    const int wn = (wv >> 1) << 7;   // N base 0/128
    const int col = lane & 31, ll5 = lane >> 5;

    int bofs0[4];
#pragma unroll
    for (int ni = 0; ni < 4; ++ni) {
        const int ln = wn + ni * 32 + col;
        const int cell = ((ln >> 5) + 2) * 40 + (ln & 31) + 4;
        bofs0[ni] = cell * 8 + ll5 * 3840;
    }
    const int rowA0 = (wm + col) * 8;
    const int oA = ll5 * 1024;

    f16v acc[2][4];
#pragma unroll
    for (int i = 0; i < 2; ++i)
#pragma unroll
        for (int j = 0; j < 4; ++j) acc[i][j] = (f16v)0.f;

    const HSeg sg = jb.s;
    const unsigned short* inb = sg.in + ((size_t)bb << (10 + sg.cl));
    const unsigned short* wissue = jb.wt;
    const int nch = sg.nch;
    const int ntot = nch * 25;

    bf8v av[2][2], bvA[2][4], bvB[2][4];

    auto issue = [&](int gt1) {
        const int sl = (gt1 & 3) * 4096;
        GLDS(wissue + tid * 8,         &sA[sl + tid * 8]);
        GLDS(wissue + (tid + 256) * 8, &sA[sl + (tid + 256) * 8]);
        wissue += 4096;
    };
    auto rdA = [&](int slot) {
        const unsigned short* sAb = &sA[slot * 4096];
#pragma unroll
        for (int s = 0; s < 2; ++s)
#pragma unroll
            for (int mi = 0; mi < 2; ++mi)
                av[s][mi] = *(const bf8v*)&sAb[s * 2048 + oA + rowA0 + mi * 256];
    };
    auto rdB = [&](bf8v (&bv)[2][4], int kk) {
        const int t5 = (kk * 52) >> 8;
        const int tO = ((t5 - 2) * 40 + (kk - t5 * 5 - 2)) * 8;
#pragma unroll
        for (int s = 0; s < 2; ++s)
#pragma unroll
            for (int ni = 0; ni < 4; ++ni)
                bv[s][ni] = *(const bf8v*)&sH[bofs0[ni] + tO + s * 7680];
    };
    auto mm = [&](bf8v (&bv)[2][4]) {
        __builtin_amdgcn_s_setprio(1);
#pragma unroll
        for (int s = 0; s < 2; ++s)
#pragma unroll
            for (int mi = 0; mi < 2; ++mi)
#pragma unroll
                for (int ni = 0; ni < 4; ++ni)
                    acc[mi][ni] = __builtin_amdgcn_mfma_f32_32x32x16_bf16(
                        av[s][mi], bv[s][ni], acc[mi][ni], 0, 0, 0);
        __builtin_amdgcn_s_setprio(0);
    };

    // ---- prologue ----
    stage_halo(sH, inb, sg.cl, sg.c0, y0, tid);
    issue(0);
    issue(1);
    asm volatile("s_waitcnt vmcnt(2) lgkmcnt(0)" ::: "memory");
    __builtin_amdgcn_s_barrier();

    for (int c = 0; c < nch; ++c) {
        const int gt0 = c * 25;
        if (c > 0) {
            __syncthreads();    // drain: all sH readers done, GLDS queue empty
            stage_halo(sH, inb, sg.cl, sg.c0 + c * 32, y0, tid);
            __syncthreads();    // all waves' sH writes visible
        }
        rdB(bvA, 0);            // prefetch B for tap 0
        for (int jj = 0; jj < 12; ++jj) {
            const int ta = gt0 + 2 * jj;
            // ---- tap ta (even): uses bvA, prefetch bvB ----
            if (ta + 2 < ntot) { issue(ta + 2); asm volatile("s_waitcnt vmcnt(2)" ::: "memory"); }
            else               {                asm volatile("s_waitcnt vmcnt(0)" ::: "memory"); }
            __builtin_amdgcn_s_barrier();
            rdA(ta & 3);
            rdB(bvB, 2 * jj + 1);
            mm(bvA);
            // ---- tap ta+1 (odd): uses bvB, prefetch bvA ----
            if (ta + 3 < ntot) { issue(ta + 3); asm volatile("s_waitcnt vmcnt(2)" ::: "memory"); }
            else               {                asm volatile("s_waitcnt vmcnt(0)" ::: "memory"); }
            __builtin_amdgcn_s_barrier();
            rdA((ta + 1) & 3);
            rdB(bvA, 2 * jj + 2);
            mm(bvB);
        }
        {   // ---- tap gt0+24 (tail, uses bvA, no prefetch) ----
            const int ta = gt0 + 24;
            if (ta + 2 < ntot) { issue(ta + 2); asm volatile("s_waitcnt vmcnt(2)" ::: "memory"); }
            else               {                asm volatile("s_waitcnt vmcnt(0)" ::: "memory"); }
            __builtin_amdgcn_s_barrier();
            rdA(ta & 3);
            mm(bvA);
        }
    }

    // epilogue (32x32 C/D): col=lane&31, row=(reg&3)+8*(reg>>2)+4*ll5
    const int nfix = ng0 + wn + col;
#pragma unroll
    for (int ni = 0; ni < 4; ++ni) {
        const int n = nfix + ni * 32;
        float* ob = jb.out + (size_t)n * jb.cout_stride;
#pragma unroll
        for (int mi = 0; mi < 2; ++mi) {
            const int mb = wm + mi * 32 + 4 * ll5;
            const f16v a = acc[mi][ni];
#pragma unroll
            for (int qd = 0; qd < 4; ++qd) {
                f4v v;
                v[0] = a[qd * 4 + 0]; v[1] = a[qd * 4 + 1];
                v[2] = a[qd * 4 + 2]; v[3] = a[qd * 4 + 3];
                *(f4v*)(ob + mb + qd * 8) = v;
            }
        }
    }
}

// ------------------------------------------------------------------
// hconv: classic 2-phase stream conv (phase B: many short jobs, 576
// blocks). sH plane layout (4 planes x 320 cells x 8 shorts).
// ------------------------------------------------------------------
template<typename JOBS>
__global__ __launch_bounds__(256) void hconv_kernel(JOBS jobs)
{
    __shared__ unsigned short sA[8192];    // 2 x 8KB tile buffers
    __shared__ unsigned short sH[10240];   // 4 planes x 320 cells x 8 shorts
    const HJob jb = jobs.j[blockIdx.y];
    const int tid = threadIdx.x;

    const int ng0 = blockIdx.x * 128;
    const int bb = ng0 >> 10, p0 = ng0 & 1023;
    const int y0 = p0 >> 5;

    const int lane = tid & 63, wv = tid >> 6;
    const int wm = (wv & 1) << 6;
    const int wn = (wv >> 1) << 6;
    const int col = lane & 31, ll5 = lane >> 5;

    int bofs0[2];
#pragma unroll
    for (int ni = 0; ni < 2; ++ni) {
        const int ln = wn + ni * 32 + col;
        const int cell = ((ln >> 5) + 2) * 40 + (ln & 31) + 4;
        bofs0[ni] = cell * 8 + ll5 * 2560;
    }

    f16v acc[2][2];
#pragma unroll
    for (int i = 0; i < 2; ++i)
#pragma unroll
        for (int j = 0; j < 2; ++j) acc[i][j] = (f16v)0.f;

    const HSeg sg = jb.s;
    const unsigned short* inb = sg.in + ((size_t)bb << (10 + sg.cl));
    const unsigned short* wptr = jb.wt;
    int buf = 0;
    bool first = true;
    for (int ch = 0; ch < sg.nch; ++ch) {
        const int c0 = sg.c0 + ch * 32;
#pragma unroll
        for (int k = 0; k < 5; ++k) {
            const int s = tid + k * 256;
            const int r = s / 160;
            const int rem = s - r * 160;
            const int cc = rem >> 2, G = rem & 3;
            const int y = y0 + r - 2, x = cc - 4;
            const bool okv = ((unsigned)y < 32u) & ((unsigned)x < 32u);
            const int yc = okv ? y : 0, xc = okv ? x : 0;
            bf8v v = *(const bf8v*)(inb + ((((yc << 5) + xc)) << sg.cl) + c0 + G * 8);
            if (!okv) v = (bf8v)(short)0;
            *(bf8v*)&sH[(G * 320 + r * 40 + cc) * 8] = v;
        }
        if (first) {
            GLDS(wptr + tid * 8,         &sA[tid * 8]);
            GLDS(wptr + (tid + 256) * 8, &sA[(tid + 256) * 8]);
            wptr += 4096;
            first = false;
        }
        __syncthreads();
        for (int t = 0; t < sg.ntaps; ++t) {
            GLDS(wptr + tid * 8,         &sA[(buf ^ 1) * 4096 + tid * 8]);
            GLDS(wptr + (tid + 256) * 8, &sA[(buf ^ 1) * 4096 + (tid + 256) * 8]);
            wptr += 4096;
            int tO = 0;
            if (sg.five) {
                const int tap = sg.tap0 + t;
                const int t5 = (tap * 52) >> 8;
                tO = ((t5 - 2) * 40 + (tap - t5 * 5 - 2)) * 8;
            }
            const unsigned short* sAb = &sA[buf * 4096];
#pragma unroll
            for (int s = 0; s < 2; ++s) {
                const int o = s * 2 + ll5;
                bf8v av[2], bv[2];
#pragma unroll
                for (int mi = 0; mi < 2; ++mi)
                    av[mi] = *(const bf8v*)&sAb[(o * 128 + wm + mi * 32 + col) * 8];
#pragma unroll
                for (int ni = 0; ni < 2; ++ni)
                    bv[ni] = *(const bf8v*)&sH[bofs0[ni] + tO + s * 5120];
#pragma unroll
                for (int mi = 0; mi < 2; ++mi)
#pragma unroll
                    for (int ni = 0; ni < 2; ++ni)
                        acc[mi][ni] = __builtin_amdgcn_mfma_f32_32x32x16_bf16(
                            av[mi], bv[ni], acc[mi][ni], 0, 0, 0);
            }
            __syncthreads();
            buf ^= 1;
        }
    }

    const int nfix = ng0 + wn + col;
#pragma unroll
    for (int ni = 0; ni < 2; ++ni) {
        const int n = nfix + ni * 32;
        float* ob = jb.out + (size_t)n * jb.cout_stride;
#pragma unroll
        for (int mi = 0; mi < 2; ++mi) {
            const int mb = wm + mi * 32 + 4 * ll5;
            const f16v a = acc[mi][ni];
#pragma unroll
            for (int qd = 0; qd < 4; ++qd) {
                f4v v;
                v[0] = a[qd * 4 + 0]; v[1] = a[qd * 4 + 1];
                v[2] = a[qd * 4 + 2]; v[3] = a[qd * 4 + 3];
                *(f4v*)(ob + mb + qd * 8) = v;
            }
        }
    }
}

// ------------------------------------------------------------------
// packT: OIHW f32 -> linear tile stream [at][oct][row][8] bf16.
// ------------------------------------------------------------------
__global__ __launch_bounds__(256) void packT_kernel(
    const float* __restrict__ src, unsigned short* __restrict__ dst,
    int Cin, int srcTaps, int rowOff, int ci0, int ntaps, int tap0,
    int ciMax, int total)
{
    const int idx = blockIdx.x * 256 + threadIdx.x;
    if (idx >= total) return;
    const int j = idx & 7;
    const int row = (idx >> 3) & 127;
    const int q = (idx >> 10) & 3;
    const int at = idx >> 12;
    const int ch = at / ntaps;
    const int tap = tap0 + (at - ch * ntaps);
    const int ci = ci0 + ch * 32 + q * 8 + j;
    float v = 0.f;
    if (ci < ciMax)
        v = src[((size_t)(rowOff + row) * Cin + ci) * srcTaps + tap];
    dst[idx] = f2bf(v);
}

__global__ __launch_bounds__(256) void net_kernel(
    const float* __restrict__ frames, const float* __restrict__ mask,
    const float* __restrict__ xgen, unsigned short* __restrict__ net, int t)
{
    const int idx = blockIdx.x * 256 + threadIdx.x;  // 8192*32
    const int n = idx >> 5, ch = idx & 31;
    float v = 0.f;
    if (ch < 16) {
        const int b = n >> 10, p = n & 1023;
        const float fr = frames[((((size_t)b * 20 + t) << 10) + p) * 16 + ch];
        if (t < TPREV) v = fr;
        else {
            const float mk = mask[((((size_t)b * 9 + (t - TPREV)) << 10) + p) * 16 + ch];
            v = mk * fr + (1.f - mk) * xgen[(size_t)n * 16 + ch];
        }
    }
    net[idx] = f2bf(v);
}

__global__ __launch_bounds__(256) void gates_kernel(
    const float* __restrict__ preA, const float* __restrict__ preB,
    float* __restrict__ c, float* __restrict__ m,
    unsigned short* __restrict__ m_bf, unsigned short* __restrict__ mem)
{
    const int idx = blockIdx.x * 256 + threadIdx.x;  // 8192*128
    const int n = idx >> 7, ch = idx & 127;
    const float* pa = preA + (size_t)n * 896 + ch;
    const float* pb = preB + (size_t)n * 896 + ch;
    const float i_ = pa[0]   + pb[0];
    const float f_ = pa[128] + pb[128];
    const float g_ = pa[256] + pb[256];
    const float ip = pa[384] + pb[384];
    const float fp = pa[512] + pb[512];
    const float gp = pa[640] + pb[640];
    const float cn = sigmoidf_(f_ + 1.f) * c[idx] + sigmoidf_(i_) * tanhf(g_);
    const float mn = sigmoidf_(fp + 1.f) * m[idx] + sigmoidf_(ip) * tanhf(gp);
    c[idx] = cn;
    m[idx] = mn;
    m_bf[idx] = f2bf(mn);
    mem[(size_t)n * 256 + ch] = f2bf(cn);
    mem[(size_t)n * 256 + 128 + ch] = f2bf(mn);
}

__global__ __launch_bounds__(256) void hout_kernel(
    const float* __restrict__ preA, const float* __restrict__ preB,
    const float* __restrict__ opart, const float* __restrict__ lconv,
    unsigned short* __restrict__ h)
{
    const int idx = blockIdx.x * 256 + threadIdx.x;  // 8192*128
    const int n = idx >> 7, ch = idx & 127;
    float oc = preA[(size_t)n * 896 + 768 + ch] + preB[(size_t)n * 896 + 768 + ch];
#pragma unroll
    for (int j = 0; j < 8; ++j) oc += opart[idx + (size_t)j * 1048576];
    h[idx] = f2bf(sigmoidf_(oc) * tanhf(lconv[idx]));
}

__global__ __launch_bounds__(256) void wout_kernel(
    const unsigned short* __restrict__ h3, const float* __restrict__ wo,
    float* __restrict__ xgen, float* __restrict__ out, int t)
{
    const int idx = blockIdx.x * 256 + threadIdx.x;  // 8192*16
    const int n = idx >> 4, ch = idx & 15;
    const int b = n >> 10, p = n & 1023;
    const unsigned short* hr = h3 + (size_t)n * 128;
    const float* wr = wo + ch * 128;
    float acc = 0.f;
#pragma unroll 8
    for (int ci = 0; ci < 128; ++ci)
        acc = fmaf(bf2f(hr[ci]), wr[ci], acc);
    xgen[idx] = acc;
    out[((((size_t)b * TT + t) << 10) + p) * 16 + ch] = acc;
}

extern "C" void kernel_launch(void* const* d_in, const int* in_sizes, int n_in,
                              void* d_out, int out_size, void* d_ws, size_t ws_size,
                              hipStream_t stream)
{
    const float* frames = (const float*)d_in[0];
    const float* mask   = (const float*)d_in[1];
    const float* Wx0    = (const float*)d_in[2];
    const float* Wx     = (const float*)d_in[3];
    const float* Wh     = (const float*)d_in[4];
    const float* Wm     = (const float*)d_in[5];
    const float* Wo     = (const float*)d_in[6];
    const float* Wl     = (const float*)d_in[7];
    const float* Wout   = (const float*)d_in[8];
    float* out = (float*)d_out;

    char* base = (char*)d_ws;
    size_t off = 0;
    auto take = [&](size_t bytes) -> char* {
        char* p = base + off;
        off = (off + bytes + 255) & ~(size_t)255;
        return p;
    };
    // ---- zero-init region ----
    float* c0            = (float*)take(4ull * 1048576 * 4);
    float* m32           = (float*)take((size_t)1048576 * 4);
    unsigned short* hbf  = (unsigned short*)take(4ull * 1048576 * 2);
    unsigned short* mbf  = (unsigned short*)take((size_t)1048576 * 2);
    const size_t zbytes = off;
    // ---- working buffers ----
    float* xgen          = (float*)take((size_t)131072 * 4);
    float* preA          = (float*)take((size_t)8192 * 896 * 4);
    float* preB          = (float*)take((size_t)8192 * 896 * 4);
    float* lconv         = (float*)take((size_t)1048576 * 4);
    float* opart         = (float*)take(8ull * 1048576 * 4);
    unsigned short* net  = (unsigned short*)take((size_t)262144 * 2);   // [8192][32]
    unsigned short* mem  = (unsigned short*)take((size_t)2097152 * 2);
    // ---- packed weights (tile streams; +4096 el pad) ----
    unsigned short* pa0xT = (unsigned short*)take(((size_t)7 * 25 * 4096 + 4096) * 2);
    unsigned short* paT0 = (unsigned short*)take(((size_t)7 * 100 * 4096 + 4096) * 2);
    unsigned short* paT1 = (unsigned short*)take(((size_t)7 * 200 * 4096 + 4096) * 2);
    unsigned short* paT2 = (unsigned short*)take(((size_t)7 * 200 * 4096 + 4096) * 2);
    unsigned short* paT3 = (unsigned short*)take(((size_t)7 * 200 * 4096 + 4096) * 2);
    unsigned short* paT[4] = { paT0, paT1, paT2, paT3 };
    unsigned short* oT   = (unsigned short*)take((4ull * 200 * 4096 + 4096) * 2);
    unsigned short* lT   = (unsigned short*)take((4ull * 8 * 4096 + 4096) * 2);

    hipMemsetAsync(d_ws, 0, zbytes, stream);

    auto packT = [&](const float* s, unsigned short* d, int Cin, int srcTaps,
                     int rowOff, int ci0, int nch, int ntaps, int tap0, int ciMax) {
        const int total = nch * ntaps * 4096;
        packT_kernel<<<(total + 255) / 256, 256, 0, stream>>>(
            s, d, Cin, srcTaps, rowOff, ci0, ntaps, tap0, ciMax, total);
    };
    const int CIMAXBIG = 1 << 30;
    for (int g = 0; g < 7; ++g) {
        packT(Wx0, pa0xT + (size_t)g * 25 * 4096, 16, 25, g * 128, 0, 1, 25, 0, 16);
        const float* hm0 = (g < 3) ? (Wh + (size_t)g * 128 * 128 * 25)
                         : (g == 6) ? (Wh + (size_t)384 * 128 * 25)
                                    : (Wm + (size_t)(g - 3) * 128 * 128 * 25);
        packT(hm0, paT0 + (size_t)g * 100 * 4096, 128, 25, 0, 0, 4, 25, 0, CIMAXBIG);
        for (int l = 1; l < 4; ++l) {
            packT(Wx + (size_t)(l - 1) * 896 * 128 * 25,
                  paT[l] + (size_t)g * 200 * 4096, 128, 25, g * 128, 0, 4, 25, 0, CIMAXBIG);
            const float* hmsrc = (g < 3) ? (Wh + ((size_t)l * 512 + g * 128) * 128 * 25)
                               : (g == 6) ? (Wh + ((size_t)l * 512 + 384) * 128 * 25)
                                          : (Wm + ((size_t)l * 384 + (g - 3) * 128) * 128 * 25);
            packT(hmsrc, paT[l] + ((size_t)g * 200 + 100) * 4096, 128, 25, 0, 0, 4, 25, 0, CIMAXBIG);
        }
    }
    for (int l = 0; l < 4; ++l) {
        packT(Wo + (size_t)l * 128 * 256 * 25, oT + (size_t)l * 200 * 4096,
              256, 25, 0, 0, 8, 25, 0, CIMAXBIG);
        packT(Wl + (size_t)l * 128 * 256, lT + (size_t)l * 8 * 4096,
              256, 1, 0, 0, 8, 1, 0, CIMAXBIG);
    }

    for (int t = 0; t < TT; ++t) {
        net_kernel<<<1024, 256, 0, stream>>>(frames, mask, xgen, net, t);
        for (int l = 0; l < 4; ++l) {
            unsigned short* hl = hbf + (size_t)l * 1048576;
            // ---- phase A: one hconvA dispatch of 14 jobs ----
            HJobs14 JA{};
            if (l == 0) {
                for (int g = 0; g < 7; ++g) {
                    const unsigned short* hmsrc = (g < 3 || g == 6) ? hl : mbf;
                    JA.j[2 * g] = HJob{ pa0xT + (size_t)g * 25 * 4096, preA + g * 128,
                                        896, 0, HSeg{ net, 5, 0, 1, 0, 25, 1 } };
                    JA.j[2 * g + 1] = HJob{ paT0 + (size_t)g * 100 * 4096, preB + g * 128,
                                            896, 0, HSeg{ hmsrc, 7, 0, 4, 0, 25, 1 } };
                }
            } else {
                for (int g = 0; g < 7; ++g) {
                    const unsigned short* hmsrc = (g < 3 || g == 6) ? hl : mbf;
                    JA.j[g] = HJob{ paT[l] + (size_t)g * 200 * 4096, preA + g * 128,
                                    896, 0, HSeg{ hbf + (size_t)(l - 1) * 1048576, 7, 0, 4, 0, 25, 1 } };
                    JA.j[7 + g] = HJob{ paT[l] + ((size_t)g * 200 + 100) * 4096, preB + g * 128,
                                        896, 0, HSeg{ hmsrc, 7, 0, 4, 0, 25, 1 } };
                }
            }
            hconvA_kernel<HJobs14><<<dim3(32, 14), 256, 0, stream>>>(JA);

            gates_kernel<<<4096, 256, 0, stream>>>(preA, preB,
                c0 + (size_t)l * 1048576, m32, mbf, mem);

            // ---- phase B: o-conv split by ci-chunk x8 + lconv (classic kernel)
            HJobs9 JB{};
            for (int jj = 0; jj < 8; ++jj)
                JB.j[jj] = HJob{ oT + ((size_t)l * 200 + jj * 25) * 4096,
                                 opart + (size_t)jj * 1048576, 128, 0,
                                 HSeg{ mem, 8, jj * 32, 1, 0, 25, 1 } };
            JB.j[8] = HJob{ lT + (size_t)l * 8 * 4096, lconv, 128, 0,
                            HSeg{ mem, 8, 0, 8, 0, 1, 0 } };
            hconv_kernel<HJobs9><<<dim3(64, 9), 256, 0, stream>>>(JB);

            hout_kernel<<<4096, 256, 0, stream>>>(preA, preB, opart, lconv, hl);
        }
        wout_kernel<<<512, 256, 0, stream>>>(hbf + (size_t)3 * 1048576, Wout, xgen, out, t);
    }
}